// Round 1
// baseline (352.356 us; speedup 1.0000x reference)
//
#include <hip/hip_runtime.h>

// ReLuGRUCell: B=16384, D_IN=1024, H=1024, fp32 in/out, bf16 MFMA internally.
//
// z = sigmoid(x@Wih0^T + h@Whh0^T + b0)
// r = sigmoid(x@Wih1^T + h@Whh1^T + b1)
// n = relu  (x@Wih2^T + (h*r)@Whh2^T + b2)
// out = (1-z)*n + z*h
//
// ws layout:
//   A  [16384][3072] bf16 : cols 0:1024=bf16(input), 1024:2048=bf16(hx),
//                           2048:3072=bf16(hx*r)   (written by gemm1 epilogue)
//   Wc [3072][2048]  bf16 : row g*1024+h = [Wih[g][h][:], Whh[g][h][:]]
//   Z  [16384][1024] bf16 : sigmoid gate z

typedef __bf16 bf16x8 __attribute__((ext_vector_type(8)));
typedef float f32x4 __attribute__((ext_vector_type(4)));

#define B_ROWS 16384
#define LDA 3072
#define LDB 2048

// ---------------- pack kernels ----------------

__global__ __launch_bounds__(256) void pack_A(const float* __restrict__ inp,
                                              const float* __restrict__ hx,
                                              __bf16* __restrict__ A) {
  int t = blockIdx.x * 256 + threadIdx.x;   // 16384*128 threads, 8 elems each
  int row = t >> 7;
  int col = (t & 127) << 3;
  const float4* pi = reinterpret_cast<const float4*>(inp + ((size_t)row << 10) + col);
  const float4* ph = reinterpret_cast<const float4*>(hx + ((size_t)row << 10) + col);
  float4 a0 = pi[0], a1 = pi[1];
  float4 b0 = ph[0], b1 = ph[1];
  bf16x8 oa, ob;
  oa[0] = (__bf16)a0.x; oa[1] = (__bf16)a0.y; oa[2] = (__bf16)a0.z; oa[3] = (__bf16)a0.w;
  oa[4] = (__bf16)a1.x; oa[5] = (__bf16)a1.y; oa[6] = (__bf16)a1.z; oa[7] = (__bf16)a1.w;
  ob[0] = (__bf16)b0.x; ob[1] = (__bf16)b0.y; ob[2] = (__bf16)b0.z; ob[3] = (__bf16)b0.w;
  ob[4] = (__bf16)b1.x; ob[5] = (__bf16)b1.y; ob[6] = (__bf16)b1.z; ob[7] = (__bf16)b1.w;
  *reinterpret_cast<bf16x8*>(A + (size_t)row * LDA + col) = oa;
  *reinterpret_cast<bf16x8*>(A + (size_t)row * LDA + 1024 + col) = ob;
}

__global__ __launch_bounds__(256) void pack_W(const float* __restrict__ wih,
                                              const float* __restrict__ whh,
                                              __bf16* __restrict__ Wc) {
  int t = blockIdx.x * 256 + threadIdx.x;   // 3072*128 threads
  int n = t >> 7;                           // weight row (g*1024+h); wih/whh flat = [3072][1024]
  int col = (t & 127) << 3;
  const float4* pi = reinterpret_cast<const float4*>(wih + ((size_t)n << 10) + col);
  const float4* ph = reinterpret_cast<const float4*>(whh + ((size_t)n << 10) + col);
  float4 a0 = pi[0], a1 = pi[1];
  float4 b0 = ph[0], b1 = ph[1];
  bf16x8 oa, ob;
  oa[0] = (__bf16)a0.x; oa[1] = (__bf16)a0.y; oa[2] = (__bf16)a0.z; oa[3] = (__bf16)a0.w;
  oa[4] = (__bf16)a1.x; oa[5] = (__bf16)a1.y; oa[6] = (__bf16)a1.z; oa[7] = (__bf16)a1.w;
  ob[0] = (__bf16)b0.x; ob[1] = (__bf16)b0.y; ob[2] = (__bf16)b0.z; ob[3] = (__bf16)b0.w;
  ob[4] = (__bf16)b1.x; ob[5] = (__bf16)b1.y; ob[6] = (__bf16)b1.z; ob[7] = (__bf16)b1.w;
  *reinterpret_cast<bf16x8*>(Wc + (size_t)n * LDB + col) = oa;
  *reinterpret_cast<bf16x8*>(Wc + (size_t)n * LDB + 1024 + col) = ob;
}

// ---------------- fused GEMM ----------------
// MODE 0: C = A[:,0:2048] @ Wc[0:2048]^T   (gates z, r) -> Z, hxr
// MODE 1: C = [input|hxr] @ Wc[2048:3072]^T (gate n)    -> out
// 128x128 tile, BK=64, 4 waves of 64x64, mfma_f32_16x16x32_bf16.
// LDS staged via global_load_lds(16B); XOR chunk-swizzle applied on the
// GLOBAL source + on the ds_read side (LDS dest stays linear — rule #21).

template <int MODE>
__global__ __launch_bounds__(256) void gemm_fused(__bf16* A,                    // read (+ hxr write in MODE 0)
                                                  const __bf16* __restrict__ Wc,
                                                  const float* __restrict__ hx,
                                                  const float* __restrict__ bias,
                                                  __bf16* __restrict__ Zbuf,
                                                  float* __restrict__ out) {
  __shared__ __attribute__((aligned(16))) __bf16 As[128 * 64];
  __shared__ __attribute__((aligned(16))) __bf16 Bs[128 * 64];

  const int tid = threadIdx.x;
  const int row0 = blockIdx.x * 128;
  const int col0 = blockIdx.y * 128;

  const __bf16* Brow = Wc + (size_t)((MODE ? 2048 : 0) + col0) * LDB;

  f32x4 acc[4][4] = {};

  const int lane = tid & 63;
  const int wid = tid >> 6;
  const int wr = wid >> 1;
  const int wc = wid & 1;

  for (int k0 = 0; k0 < 2048; k0 += 64) {
    const int kA = (MODE == 1 && k0 >= 1024) ? k0 + 1024 : k0;  // skip hx cols in MODE 1
    // ---- stage A tile [128][64] ----
#pragma unroll
    for (int i = 0; i < 4; ++i) {
      int idx = i * 256 + tid;          // 16B chunk index, 0..1023
      int r = idx >> 3;
      int c = idx & 7;
      int sc = c ^ (r & 7);             // pre-swizzled source chunk
      const __bf16* g = A + (size_t)(row0 + r) * LDA + kA + sc * 8;
      __builtin_amdgcn_global_load_lds((const __attribute__((address_space(1))) void*)g,
                                       (__attribute__((address_space(3))) void*)(As + idx * 8),
                                       16, 0, 0);
    }
    // ---- stage B tile [128][64] ----
#pragma unroll
    for (int i = 0; i < 4; ++i) {
      int idx = i * 256 + tid;
      int r = idx >> 3;
      int c = idx & 7;
      int sc = c ^ (r & 7);
      const __bf16* g = Brow + (size_t)r * LDB + k0 + sc * 8;
      __builtin_amdgcn_global_load_lds((const __attribute__((address_space(1))) void*)g,
                                       (__attribute__((address_space(3))) void*)(Bs + idx * 8),
                                       16, 0, 0);
    }
    __syncthreads();   // compiler emits vmcnt(0) drain before barrier

    // ---- compute: 2 k-slices of 32, 16 MFMA each ----
#pragma unroll
    for (int kk = 0; kk < 2; ++kk) {
      bf16x8 af[4], bfr[4];
#pragma unroll
      for (int m = 0; m < 4; ++m) {
        int r = wr * 64 + m * 16 + (lane & 15);
        int c = kk * 4 + (lane >> 4);
        af[m] = *reinterpret_cast<const bf16x8*>(As + r * 64 + (c ^ (r & 7)) * 8);
      }
#pragma unroll
      for (int n = 0; n < 4; ++n) {
        int r = wc * 64 + n * 16 + (lane & 15);
        int c = kk * 4 + (lane >> 4);
        bfr[n] = *reinterpret_cast<const bf16x8*>(Bs + r * 64 + (c ^ (r & 7)) * 8);
      }
#pragma unroll
      for (int m = 0; m < 4; ++m)
#pragma unroll
        for (int n = 0; n < 4; ++n)
          acc[m][n] = __builtin_amdgcn_mfma_f32_16x16x32_bf16(af[m], bfr[n], acc[m][n], 0, 0, 0);
    }
    __syncthreads();
  }

  // ---- epilogue ----
  // C/D layout (m89-verified): col = lane&15, row = (lane>>4)*4 + j
#pragma unroll
  for (int m = 0; m < 4; ++m) {
#pragma unroll
    for (int n = 0; n < 4; ++n) {
      int col = col0 + wc * 64 + n * 16 + (lane & 15);
      int rbase = row0 + wr * 64 + m * 16 + (lane >> 4) * 4;
      if (MODE == 0) {
        int gate = col >> 10;         // 0 -> z, 1 -> r   (uniform per (m,n) tile)
        int h = col & 1023;
        float b = bias[gate * 1024 + h];
#pragma unroll
        for (int j = 0; j < 4; ++j) {
          int rg = rbase + j;
          float x = acc[m][n][j] + b;
          float s = 1.f / (1.f + __expf(-x));
          if (gate == 0) {
            Zbuf[(size_t)rg * 1024 + h] = (__bf16)s;
          } else {
            float hv = hx[(size_t)rg * 1024 + h];
            A[(size_t)rg * LDA + 2048 + h] = (__bf16)(hv * s);
          }
        }
      } else {
        int h = col;                  // 0..1023
        float b = bias[2048 + h];
#pragma unroll
        for (int j = 0; j < 4; ++j) {
          int rg = rbase + j;
          float np = fmaxf(acc[m][n][j] + b, 0.f);
          float z = (float)Zbuf[(size_t)rg * 1024 + h];
          float hv = hx[(size_t)rg * 1024 + h];
          out[(size_t)rg * 1024 + h] = (1.f - z) * np + z * hv;
        }
      }
    }
  }
}

// ---------------- launch ----------------

extern "C" void kernel_launch(void* const* d_in, const int* in_sizes, int n_in,
                              void* d_out, int out_size, void* d_ws, size_t ws_size,
                              hipStream_t stream) {
  const float* inp  = (const float*)d_in[0];
  const float* hx   = (const float*)d_in[1];
  const float* wih  = (const float*)d_in[2];
  const float* whh  = (const float*)d_in[3];
  const float* bias = (const float*)d_in[4];
  float* out = (float*)d_out;

  char* ws = (char*)d_ws;
  __bf16* A  = (__bf16*)ws;                                  // 100,663,296 B
  __bf16* Wc = (__bf16*)(ws + 100663296);                    //  12,582,912 B
  __bf16* Z  = (__bf16*)(ws + 100663296 + 12582912);         //  33,554,432 B

  pack_A<<<8192, 256, 0, stream>>>(inp, hx, A);
  pack_W<<<1536, 256, 0, stream>>>(wih, whh, Wc);

  dim3 g1(B_ROWS / 128, 2048 / 128);   // 128 x 16
  gemm_fused<0><<<g1, 256, 0, stream>>>(A, Wc, hx, bias, Z, out);

  dim3 g2(B_ROWS / 128, 1024 / 128);   // 128 x 8
  gemm_fused<1><<<g2, 256, 0, stream>>>(A, Wc, hx, bias, Z, out);
}

// Round 2
// 282.916 us; speedup vs baseline: 1.2454x; 1.2454x over previous
//
#include <hip/hip_runtime.h>

// ReLuGRUCell: B=16384, D_IN=1024, H=1024, fp32 in/out, bf16 MFMA internally.
// Round 2: 256x256 8-phase GEMM template (T2 swizzle + T3/T4 counted vmcnt + T5 setprio).
//
// ws layout:
//   A  [16384][3072] bf16 : cols 0:1024=bf16(input), 1024:2048=bf16(hx), 2048:3072=bf16(hx*r)
//   Wc [3072][2048]  bf16 : row g*1024+h = [Wih[g][h][:], Whh[g][h][:]]
//   Z  [16384][1024] bf16 : sigmoid gate z

typedef __bf16 bf16x8 __attribute__((ext_vector_type(8)));
typedef float f32x4 __attribute__((ext_vector_type(4)));

#define LDA 3072
#define LDB 2048
#define HALF 8192  // elems in one [128][64] bf16 half-tile (16 KiB)

// ---------------- pack kernels ----------------

__global__ __launch_bounds__(256) void pack_A(const float* __restrict__ inp,
                                              const float* __restrict__ hx,
                                              __bf16* __restrict__ A) {
  int t = blockIdx.x * 256 + threadIdx.x;
  int row = t >> 7;
  int col = (t & 127) << 3;
  const float4* pi = reinterpret_cast<const float4*>(inp + ((size_t)row << 10) + col);
  const float4* ph = reinterpret_cast<const float4*>(hx + ((size_t)row << 10) + col);
  float4 a0 = pi[0], a1 = pi[1];
  float4 b0 = ph[0], b1 = ph[1];
  bf16x8 oa, ob;
  oa[0] = (__bf16)a0.x; oa[1] = (__bf16)a0.y; oa[2] = (__bf16)a0.z; oa[3] = (__bf16)a0.w;
  oa[4] = (__bf16)a1.x; oa[5] = (__bf16)a1.y; oa[6] = (__bf16)a1.z; oa[7] = (__bf16)a1.w;
  ob[0] = (__bf16)b0.x; ob[1] = (__bf16)b0.y; ob[2] = (__bf16)b0.z; ob[3] = (__bf16)b0.w;
  ob[4] = (__bf16)b1.x; ob[5] = (__bf16)b1.y; ob[6] = (__bf16)b1.z; ob[7] = (__bf16)b1.w;
  *reinterpret_cast<bf16x8*>(A + (size_t)row * LDA + col) = oa;
  *reinterpret_cast<bf16x8*>(A + (size_t)row * LDA + 1024 + col) = ob;
}

__global__ __launch_bounds__(256) void pack_W(const float* __restrict__ wih,
                                              const float* __restrict__ whh,
                                              __bf16* __restrict__ Wc) {
  int t = blockIdx.x * 256 + threadIdx.x;
  int n = t >> 7;
  int col = (t & 127) << 3;
  const float4* pi = reinterpret_cast<const float4*>(wih + ((size_t)n << 10) + col);
  const float4* ph = reinterpret_cast<const float4*>(whh + ((size_t)n << 10) + col);
  float4 a0 = pi[0], a1 = pi[1];
  float4 b0 = ph[0], b1 = ph[1];
  bf16x8 oa, ob;
  oa[0] = (__bf16)a0.x; oa[1] = (__bf16)a0.y; oa[2] = (__bf16)a0.z; oa[3] = (__bf16)a0.w;
  oa[4] = (__bf16)a1.x; oa[5] = (__bf16)a1.y; oa[6] = (__bf16)a1.z; oa[7] = (__bf16)a1.w;
  ob[0] = (__bf16)b0.x; ob[1] = (__bf16)b0.y; ob[2] = (__bf16)b0.z; ob[3] = (__bf16)b0.w;
  ob[4] = (__bf16)b1.x; ob[5] = (__bf16)b1.y; ob[6] = (__bf16)b1.z; ob[7] = (__bf16)b1.w;
  *reinterpret_cast<bf16x8*>(Wc + (size_t)n * LDB + col) = oa;
  *reinterpret_cast<bf16x8*>(Wc + (size_t)n * LDB + 1024 + col) = ob;
}

// ---------------- 8-phase GEMM helpers ----------------

__device__ __forceinline__ void stage_half(const __bf16* g0, size_t ldg, __bf16* lh, int tid) {
  // [128][64] bf16 half-tile; LDS dest linear (gload_lds constraint), source
  // chunk pre-swizzled with the same XOR used on the ds_read side (rule #21).
#pragma unroll
  for (int ld = 0; ld < 2; ++ld) {
    int idx = ld * 512 + tid;  // 16B chunk index 0..1023
    int r = idx >> 3;
    int c = idx & 7;
    int sc = c ^ (r & 7);
    const __bf16* g = g0 + (size_t)r * ldg + sc * 8;
    __builtin_amdgcn_global_load_lds((const __attribute__((address_space(1))) void*)g,
                                     (__attribute__((address_space(3))) void*)(lh + idx * 8),
                                     16, 0, 0);
  }
}

__device__ __forceinline__ void ldA(const __bf16* sAh, int p, int lane, bf16x8 (&af)[2][2]) {
#pragma unroll
  for (int m = 0; m < 2; ++m)
#pragma unroll
    for (int kk = 0; kk < 2; ++kk) {
      int rr = p * 32 + m * 16 + (lane & 15);
      int c = kk * 4 + (lane >> 4);
      af[m][kk] = *reinterpret_cast<const bf16x8*>(sAh + (rr * 8 + (c ^ (rr & 7))) * 8);
    }
}

__device__ __forceinline__ void ldB(const __bf16* sBh, int wcl, int lane, bf16x8 (&bfr)[4][2]) {
#pragma unroll
  for (int n = 0; n < 4; ++n)
#pragma unroll
    for (int kk = 0; kk < 2; ++kk) {
      int rr = wcl + n * 16 + (lane & 15);
      int c = kk * 4 + (lane >> 4);
      bfr[n][kk] = *reinterpret_cast<const bf16x8*>(sBh + (rr * 8 + (c ^ (rr & 7))) * 8);
    }
}

__device__ __forceinline__ void mfma16(const bf16x8 (&af)[2][2], const bf16x8 (&bfr)[4][2],
                                       f32x4 (&acc)[8][4], int p) {
  __builtin_amdgcn_s_setprio(1);
#pragma unroll
  for (int m = 0; m < 2; ++m)
#pragma unroll
    for (int n = 0; n < 4; ++n)
#pragma unroll
      for (int kk = 0; kk < 2; ++kk)
        acc[p * 2 + m][n] =
            __builtin_amdgcn_mfma_f32_16x16x32_bf16(af[m][kk], bfr[n][kk], acc[p * 2 + m][n], 0, 0, 0);
  __builtin_amdgcn_s_setprio(0);
}

// ---------------- fused 8-phase GEMM ----------------
// MODE 0: C = A[:,0:2048] @ Wc[0:2048]^T   -> z (Zbuf), r -> hxr (A cols 2048+)
// MODE 1: C = [input|hxr] @ Wc[2048:3072]^T -> out
// 256x256 tile, BK=64, 8 waves (2Mx4N), per-wave 128x64 output.
// LDS: [parity][half] halves for A and B = 128 KiB, double-buffered at K-tile parity.
// Stage order per iter i (E=2i ph1-4, O=2i+1 ph5-8):
//   ph1: O.A0  ph2: O.A1  ph3: (E+2).B0  ph4: (E+2).B1 + vmcnt(4)
//   ph5: (E+2).A0  ph6: (E+2).A1  ph7: (O+2).B0  ph8: (O+2).B1 + vmcnt(4)
// Every half is >=3 stages old at the vmcnt guarding its first read; every
// slot's overwrite is issued after its last read completed (lgkm before MFMA)
// + barrier. Tail stages wrap (t&31) to keep vmcnt counts uniform.

template <int MODE>
__global__ __launch_bounds__(512, 2) void gemm8(__bf16* A, const __bf16* __restrict__ Wc,
                                                const float* __restrict__ hx,
                                                const float* __restrict__ bias,
                                                __bf16* __restrict__ Zbuf,
                                                float* __restrict__ out) {
  extern __shared__ char smem[];
  __bf16* sA = (__bf16*)smem;             // [2 parity][2 half][HALF]
  __bf16* sB = (__bf16*)smem + 4 * HALF;  // [2 parity][2 half][HALF]

  const int tid = threadIdx.x;
  const int lane = tid & 63;
  const int wid = tid >> 6;
  const int wr = wid >> 2;        // 0..1  (M)
  const int wc = wid & 3;         // 0..3  (N)
  const int wcl = (wc & 1) * 64;  // col offset within B half

  const int row0 = blockIdx.x * 256;
  const int col0 = blockIdx.y * 256;

  const __bf16* Abase = A + (size_t)row0 * LDA;
  const __bf16* Bbase = Wc + (size_t)((MODE ? 2048 : 0) + col0) * LDB;

  f32x4 acc[8][4] = {};

  auto stageA = [&](int t, int h) {
    int tw = t & 31;
    int k = (MODE && tw >= 16) ? tw * 64 + 1024 : tw * 64;  // MODE1 skips hx cols
    stage_half(Abase + (size_t)(h * 128) * LDA + k, LDA, sA + (((t & 1) << 1) + h) * HALF, tid);
  };
  auto stageB = [&](int t, int h) {
    int tw = t & 31;
    stage_half(Bbase + (size_t)(h * 128) * LDB + tw * 64, LDB, sB + (((t & 1) << 1) + h) * HALF, tid);
  };

  const __bf16* sAE = sA + wr * HALF;
  const __bf16* sAO = sA + (2 + wr) * HALF;
  const __bf16* sBE = sB + (wc >> 1) * HALF;
  const __bf16* sBO = sB + (2 + (wc >> 1)) * HALF;

  // prologue: tile0 complete + tile1.B in flight
  stageA(0, 0); stageA(0, 1); stageB(0, 0); stageB(0, 1);
  stageB(1, 0); stageB(1, 1);
  asm volatile("s_waitcnt vmcnt(4)" ::: "memory");
  __builtin_amdgcn_s_barrier();

  for (int i = 0; i < 16; ++i) {
    const int O = 2 * i + 1, EN = 2 * i + 2, ON = 2 * i + 3;
    bf16x8 af[2][2], bfE[4][2], bfO[4][2];
    // ph1
    ldA(sAE, 0, lane, af); ldB(sBE, wcl, lane, bfE);
    stageA(O, 0);
    __builtin_amdgcn_s_barrier();
    mfma16(af, bfE, acc, 0);
    __builtin_amdgcn_s_barrier();
    // ph2
    ldA(sAE, 1, lane, af);
    stageA(O, 1);
    __builtin_amdgcn_s_barrier();
    mfma16(af, bfE, acc, 1);
    __builtin_amdgcn_s_barrier();
    // ph3
    ldA(sAE, 2, lane, af);
    stageB(EN, 0);
    __builtin_amdgcn_s_barrier();
    mfma16(af, bfE, acc, 2);
    __builtin_amdgcn_s_barrier();
    // ph4
    ldA(sAE, 3, lane, af);
    stageB(EN, 1);
    asm volatile("s_waitcnt vmcnt(4)" ::: "memory");
    __builtin_amdgcn_s_barrier();
    mfma16(af, bfE, acc, 3);
    __builtin_amdgcn_s_barrier();
    // ph5
    ldA(sAO, 0, lane, af); ldB(sBO, wcl, lane, bfO);
    stageA(EN, 0);
    __builtin_amdgcn_s_barrier();
    mfma16(af, bfO, acc, 0);
    __builtin_amdgcn_s_barrier();
    // ph6
    ldA(sAO, 1, lane, af);
    stageA(EN, 1);
    __builtin_amdgcn_s_barrier();
    mfma16(af, bfO, acc, 1);
    __builtin_amdgcn_s_barrier();
    // ph7
    ldA(sAO, 2, lane, af);
    stageB(ON, 0);
    __builtin_amdgcn_s_barrier();
    mfma16(af, bfO, acc, 2);
    __builtin_amdgcn_s_barrier();
    // ph8
    ldA(sAO, 3, lane, af);
    stageB(ON, 1);
    asm volatile("s_waitcnt vmcnt(4)" ::: "memory");
    __builtin_amdgcn_s_barrier();
    mfma16(af, bfO, acc, 3);
    __builtin_amdgcn_s_barrier();
  }
  asm volatile("s_waitcnt vmcnt(0)" ::: "memory");

  // ---- epilogue: C/D layout col=lane&15, row=(lane>>4)*4+j ----
#pragma unroll
  for (int m = 0; m < 8; ++m) {
#pragma unroll
    for (int n = 0; n < 4; ++n) {
      int col = col0 + wc * 64 + n * 16 + (lane & 15);
      int rbase = row0 + wr * 128 + m * 16 + (lane >> 4) * 4;
      if (MODE == 0) {
        int gate = col >> 10;  // 0 -> z, 1 -> r (uniform per block)
        int h = col & 1023;
        float b = bias[gate * 1024 + h];
#pragma unroll
        for (int j = 0; j < 4; ++j) {
          int rg = rbase + j;
          float x = acc[m][n][j] + b;
          float s = 1.f / (1.f + __expf(-x));
          if (gate == 0) {
            Zbuf[(size_t)rg * 1024 + h] = (__bf16)s;
          } else {
            float hv = hx[(size_t)rg * 1024 + h];
            A[(size_t)rg * LDA + 2048 + h] = (__bf16)(hv * s);
          }
        }
      } else {
        float b = bias[2048 + col];
#pragma unroll
        for (int j = 0; j < 4; ++j) {
          int rg = rbase + j;
          float np = fmaxf(acc[m][n][j] + b, 0.f);
          float z = (float)Zbuf[(size_t)rg * 1024 + col];
          float hv = hx[(size_t)rg * 1024 + col];
          out[(size_t)rg * 1024 + col] = (1.f - z) * np + z * hv;
        }
      }
    }
  }
}

// ---------------- launch ----------------

extern "C" void kernel_launch(void* const* d_in, const int* in_sizes, int n_in,
                              void* d_out, int out_size, void* d_ws, size_t ws_size,
                              hipStream_t stream) {
  const float* inp  = (const float*)d_in[0];
  const float* hx   = (const float*)d_in[1];
  const float* wih  = (const float*)d_in[2];
  const float* whh  = (const float*)d_in[3];
  const float* bias = (const float*)d_in[4];
  float* out = (float*)d_out;

  char* ws = (char*)d_ws;
  __bf16* A  = (__bf16*)ws;                           // 100,663,296 B
  __bf16* Wc = (__bf16*)(ws + 100663296);             //  12,582,912 B
  __bf16* Z  = (__bf16*)(ws + 100663296 + 12582912);  //  33,554,432 B

  (void)hipFuncSetAttribute((const void*)gemm8<0>, hipFuncAttributeMaxDynamicSharedMemorySize, 131072);
  (void)hipFuncSetAttribute((const void*)gemm8<1>, hipFuncAttributeMaxDynamicSharedMemorySize, 131072);

  pack_A<<<8192, 256, 0, stream>>>(inp, hx, A);
  pack_W<<<1536, 256, 0, stream>>>(wih, whh, Wc);

  dim3 g1(16384 / 256, 2048 / 256);  // 64 x 8 = 512 blocks
  gemm8<0><<<g1, 512, 131072, stream>>>(A, Wc, hx, bias, Z, out);

  dim3 g2(16384 / 256, 1024 / 256);  // 64 x 4 = 256 blocks
  gemm8<1><<<g2, 512, 131072, stream>>>(A, Wc, hx, bias, Z, out);
}